// Round 10
// baseline (176.576 us; speedup 1.0000x reference)
//
#include <hip/hip_runtime.h>

typedef _Float16 f16x8 __attribute__((ext_vector_type(8)));
typedef __fp16 fp16x2 __attribute__((ext_vector_type(2)));
typedef float f32x4 __attribute__((ext_vector_type(4)));

#define NTHR 256
constexpr float EPS = 1e-5f;
constexpr int NBLOCKS = 1024;   // 1024 blocks x 4 groups x 256 rows = 1048576

// ---- ws byte offsets ----
#define TAB_B   0       // f16 [29][8]  embedding-MLP table
#define W1_B    1024    // f16 [48][64]  fc1 (bn1+cbn folded, bias at k=36)
#define W2_B    7168    // f16 [32][64]  fc2 (bn2 folded, bias at k=36)
#define W3_B    11264   // f16 [16][32]  fc3 (bn3 folded, bias at k=18)
#define W4_B    12736   // f32 [16]  fc4 delta row (w 0..8, bias at 9)

__device__ __forceinline__ ushort f16bits(float x) {
    union { _Float16 h; ushort u; } c; c.h = (_Float16)x; return c.u;
}
__device__ __forceinline__ uint pk2(float a, float b) {
    union { fp16x2 h; uint u; } c; c.h = __builtin_amdgcn_cvt_pkrtz(a, b); return c.u;
}
__device__ __forceinline__ uint pkrelu(float a, float b) {
    return pk2(fmaxf(a, 0.f), fmaxf(b, 0.f));
}
__device__ __forceinline__ f16x8 mk8(uint a, uint b, uint c, uint d) {
    union { uint u[4]; f16x8 v; } f;
    f.u[0] = a; f.u[1] = b; f.u[2] = c; f.u[3] = d;
    return f.v;
}
__device__ __forceinline__ f16x8 ldw_frag(const ushort* wp, int m, int stride, int kb, int g) {
    const ushort* p = wp + m * stride + kb + 4 * g;
    uint2 lo = *(const uint2*)p;
    uint2 hi = *(const uint2*)(p + 16);
    return mk8(lo.x, lo.y, hi.x, hi.y);
}

__global__ __launch_bounds__(NTHR) void prep_kernel(
    const float* __restrict__ embt, const float* __restrict__ w1,
    const float* __restrict__ b1,   const float* __restrict__ w2,
    const float* __restrict__ b2,
    const float* __restrict__ cbn_g, const float* __restrict__ cbn_b,
    const float* __restrict__ cbn_m, const float* __restrict__ cbn_v,
    const float* __restrict__ f1w, const float* __restrict__ f1b,
    const float* __restrict__ f2w, const float* __restrict__ f2b,
    const float* __restrict__ f3w, const float* __restrict__ f3b,
    const float* __restrict__ f4w, const float* __restrict__ f4b,
    const float* __restrict__ bn1g, const float* __restrict__ bn1b,
    const float* __restrict__ bn1m, const float* __restrict__ bn1v,
    const float* __restrict__ bn2g, const float* __restrict__ bn2b,
    const float* __restrict__ bn2m, const float* __restrict__ bn2v,
    const float* __restrict__ bn3g, const float* __restrict__ bn3b,
    const float* __restrict__ bn3m, const float* __restrict__ bn3v,
    char* __restrict__ ws)
{
    const int t = threadIdx.x;
    ushort* tab = (ushort*)(ws + TAB_B);
    ushort* w1o = (ushort*)(ws + W1_B);
    ushort* w2o = (ushort*)(ws + W2_B);
    ushort* w3o = (ushort*)(ws + W3_B);
    float* w4o = (float*)(ws + W4_B);

    for (int i = t; i < 232; i += NTHR) {
        int j = i / 8, c = i % 8;
        float xe = 0.f;
        if (c < 5) {
            xe = b2[j];
            for (int e = 0; e < 6; e++) {
                float a = b1[j * 6 + e];
                for (int d = 0; d < 6; d++)
                    a += embt[(j * 5 + c) * 6 + d] * w1[j * 36 + d * 6 + e];
                xe += fmaxf(a, 0.f) * w2[j * 6 + e];
            }
        }
        tab[i] = f16bits(xe);
    }
    for (int i = t; i < 3072; i += NTHR) {
        int n = i / 64, k = i % 64;
        float v = 0.f;
        if (n < 36) {
            float s1 = bn1g[n] * rsqrtf(bn1v[n] + EPS);
            if (k < 36) {
                v = f1w[n * 36 + k] * s1;
                if (k < 7) v *= cbn_g[k] * rsqrtf(cbn_v[k] + EPS);
            } else if (k == 36) {
                v = f1b[n] * s1 + bn1b[n] - bn1m[n] * s1;
                for (int kk = 0; kk < 7; kk++) {
                    float cs = cbn_g[kk] * rsqrtf(cbn_v[kk] + EPS);
                    float ct = cbn_b[kk] - cbn_m[kk] * cs;
                    v += f1w[n * 36 + kk] * s1 * ct;
                }
            }
        } else if (n == 36 && k == 36) {
            v = 1.f;
        }
        w1o[i] = f16bits(v);
    }
    for (int i = t; i < 2048; i += NTHR) {
        int n = i / 64, k = i % 64;
        float v = 0.f;
        if (n < 18) {
            float s = bn2g[n] * rsqrtf(bn2v[n] + EPS);
            if (k < 36) v = f2w[n * 36 + k] * s;
            else if (k == 36) v = f2b[n] * s + bn2b[n] - bn2m[n] * s;
        } else if (n == 18 && k == 36) {
            v = 1.f;
        }
        w2o[i] = f16bits(v);
    }
    for (int i = t; i < 512; i += NTHR) {
        int n = i / 32, k = i % 32;
        float v = 0.f;
        if (n < 9) {
            float s = bn3g[n] * rsqrtf(bn3v[n] + EPS);
            if (k < 18) v = f3w[n * 18 + k] * s;
            else if (k == 18) v = f3b[n] * s + bn3b[n] - bn3m[n] * s;
        } else if (n == 9 && k == 18) {
            v = 1.f;
        }
        w3o[i] = f16bits(v);
    }
    if (t < 16) w4o[t] = (t < 9) ? (f4w[9 + t] - f4w[t]) : (t == 9 ? (f4b[1] - f4b[0]) : 0.f);
}

#define XSTRIDE 72

__global__ __launch_bounds__(NTHR, 4) void recovery_net_kernel(
    const float* __restrict__ xcon, const int* __restrict__ xcat,
    const char* __restrict__ ws, float2* __restrict__ out)
{
    __shared__ __align__(16) char s_x[2][256 * XSTRIDE];   // 36864 B double-buffered

    const int t = threadIdx.x;
    const int lane = t & 63, w = t >> 6;
    const int l15 = lane & 15, gq = lane >> 4;
    const int rb = w * 64;
    const ushort* tabh = (const ushort*)(ws + TAB_B);
    const size_t blkrow = (size_t)blockIdx.x * 1024;

    // ---- prefetch registers for one group's wave-slice ----
    int4 p0, p1, p2, p3, p4, p5, p6, p7;
    float4 f0, f1;

#define LOADREGS(G) do { \
        const int4* sc_ = (const int4*)(xcat + (blkrow + (size_t)(G) * 256 + w * 64) * 29); \
        p0 = sc_[lane];       p1 = sc_[lane + 64];  p2 = sc_[lane + 128]; \
        p3 = sc_[lane + 192]; p4 = sc_[lane + 256]; p5 = sc_[lane + 320]; \
        p6 = sc_[lane + 384]; \
        p7 = (lane < 16) ? sc_[lane + 448] : make_int4(0, 0, 0, 0); \
        const float4* sf_ = (const float4*)(xcon + (blkrow + (size_t)(G) * 256 + w * 64) * 7); \
        f0 = sf_[lane]; \
        f1 = (lane < 48) ? sf_[lane + 64] : make_float4(0.f, 0.f, 0.f, 0.f); \
    } while (0)

    LOADREGS(0);   // issue input loads first (HBM latency)

    // ---- weights resident in registers (L2-hot, loaded once) ----
    const ushort* w1p = (const ushort*)(ws + W1_B);
    const ushort* w2p = (const ushort*)(ws + W2_B);
    const ushort* w3p = (const ushort*)(ws + W3_B);
    f16x8 a1[3][2], a2[2][2], a3;
#pragma unroll
    for (int mt = 0; mt < 3; mt++) {
        a1[mt][0] = ldw_frag(w1p, mt * 16 + l15, 64, 0, gq);
        a1[mt][1] = ldw_frag(w1p, mt * 16 + l15, 64, 32, gq);
    }
#pragma unroll
    for (int mt = 0; mt < 2; mt++) {
        a2[mt][0] = ldw_frag(w2p, mt * 16 + l15, 64, 0, gq);
        a2[mt][1] = ldw_frag(w2p, mt * 16 + l15, 64, 32, gq);
    }
    a3 = ldw_frag(w3p, l15, 32, 0, gq);
    const float4 w4v = *(const float4*)((const float*)(ws + W4_B) + 4 * gq);

#pragma unroll 1
    for (int grp = 0; grp < 4; grp++) {
        char* xb = &s_x[grp & 1][0];

        // ---- scatter this group's registers into the wave-private LDS strip ----
        {
            auto scat_cat = [&](int4 v, int ibase) {
#pragma unroll
                for (int e = 0; e < 4; e++) {
                    int i = ibase + e;
                    unsigned r = (unsigned)i / 29u;
                    unsigned j = (unsigned)i - r * 29u;
                    int c = (e == 0) ? v.x : (e == 1) ? v.y : (e == 2) ? v.z : v.w;
                    *(ushort*)(xb + (rb + r) * XSTRIDE + 14 + 2 * j) = tabh[j * 8 + c];
                }
            };
            scat_cat(p0, 4 * lane);
            scat_cat(p1, 4 * lane + 256);
            scat_cat(p2, 4 * lane + 512);
            scat_cat(p3, 4 * lane + 768);
            scat_cat(p4, 4 * lane + 1024);
            scat_cat(p5, 4 * lane + 1280);
            scat_cat(p6, 4 * lane + 1536);
            if (lane < 16) scat_cat(p7, 4 * lane + 1792);
            auto scat_con = [&](float4 v, int ibase) {
#pragma unroll
                for (int e = 0; e < 4; e++) {
                    int i = ibase + e;
                    unsigned r = (unsigned)i / 7u;
                    unsigned k = (unsigned)i - r * 7u;
                    float f = (e == 0) ? v.x : (e == 1) ? v.y : (e == 2) ? v.z : v.w;
                    *(ushort*)(xb + (rb + r) * XSTRIDE + 2 * k) = f16bits(f);
                }
            };
            scat_con(f0, 4 * lane);
            if (lane < 48) scat_con(f1, 256 + 4 * lane);
        }

        // ---- issue next group's global loads (hide under compute) ----
        if (grp < 3) LOADREGS(grp + 1);

        asm volatile("s_waitcnt lgkmcnt(0)" ::: "memory");
        __builtin_amdgcn_wave_barrier();

        // ---- compute 4 batch tiles of 16 rows ----
#pragma unroll
        for (int bt = 0; bt < 4; bt++) {
            const char* xr = xb + (rb + 16 * bt + l15) * XSTRIDE;
            uint2 q0 = *(const uint2*)(xr + 8 * gq);
            uint2 q1 = *(const uint2*)(xr + 32 + 8 * gq);
            uint2 q2 = *(const uint2*)(xr + 64);
            f16x8 xb0 = mk8(q0.x, q0.y, q1.x, q1.y);
            uint cw0 = (gq == 0) ? q2.x : (gq == 1 ? 0x00003C00u : 0u);
            uint cw1 = (gq == 0) ? q2.y : 0u;
            f16x8 xb1 = mk8(cw0, cw1, 0u, 0u);

            f32x4 c10 = {0.f, 0.f, 0.f, 0.f};
            f32x4 c11 = {0.f, 0.f, 0.f, 0.f};
            f32x4 c12 = {0.f, 0.f, 0.f, 0.f};
            c10 = __builtin_amdgcn_mfma_f32_16x16x32_f16(a1[0][0], xb0, c10, 0, 0, 0);
            c11 = __builtin_amdgcn_mfma_f32_16x16x32_f16(a1[1][0], xb0, c11, 0, 0, 0);
            c12 = __builtin_amdgcn_mfma_f32_16x16x32_f16(a1[2][0], xb0, c12, 0, 0, 0);
            c10 = __builtin_amdgcn_mfma_f32_16x16x32_f16(a1[0][1], xb1, c10, 0, 0, 0);
            c11 = __builtin_amdgcn_mfma_f32_16x16x32_f16(a1[1][1], xb1, c11, 0, 0, 0);
            c12 = __builtin_amdgcn_mfma_f32_16x16x32_f16(a1[2][1], xb1, c12, 0, 0, 0);

            f16x8 h0 = mk8(pkrelu(c10.x, c10.y), pkrelu(c10.z, c10.w),
                           pkrelu(c11.x, c11.y), pkrelu(c11.z, c11.w));
            f16x8 h1 = mk8(pkrelu(c12.x, c12.y), pkrelu(c12.z, c12.w), 0u, 0u);

            f32x4 c20 = {0.f, 0.f, 0.f, 0.f};
            f32x4 c21 = {0.f, 0.f, 0.f, 0.f};
            c20 = __builtin_amdgcn_mfma_f32_16x16x32_f16(a2[0][0], h0, c20, 0, 0, 0);
            c21 = __builtin_amdgcn_mfma_f32_16x16x32_f16(a2[1][0], h0, c21, 0, 0, 0);
            c20 = __builtin_amdgcn_mfma_f32_16x16x32_f16(a2[0][1], h1, c20, 0, 0, 0);
            c21 = __builtin_amdgcn_mfma_f32_16x16x32_f16(a2[1][1], h1, c21, 0, 0, 0);

            f16x8 h2 = mk8(pkrelu(c20.x, c20.y), pkrelu(c20.z, c20.w),
                           pkrelu(c21.x, c21.y), pkrelu(c21.z, c21.w));
            f32x4 c3 = {0.f, 0.f, 0.f, 0.f};
            c3 = __builtin_amdgcn_mfma_f32_16x16x32_f16(a3, h2, c3, 0, 0, 0);

            float part = fmaxf(c3.x, 0.f) * w4v.x + fmaxf(c3.y, 0.f) * w4v.y +
                         fmaxf(c3.z, 0.f) * w4v.z + fmaxf(c3.w, 0.f) * w4v.w;
            part += __shfl_xor(part, 16);
            part += __shfl_xor(part, 32);
            float p1v = 1.f / (1.f + __expf(-part));
            if (gq == 0)
                out[blkrow + grp * 256 + rb + 16 * bt + l15] = make_float2(1.f - p1v, p1v);
        }
        __builtin_amdgcn_wave_barrier();
    }
#undef LOADREGS
}

extern "C" void kernel_launch(void* const* d_in, const int* in_sizes, int n_in,
                              void* d_out, int out_size, void* d_ws, size_t ws_size,
                              hipStream_t stream) {
    (void)in_sizes; (void)n_in; (void)ws_size; (void)out_size;
    char* ws = (char*)d_ws;
    prep_kernel<<<1, NTHR, 0, stream>>>(
        (const float*)d_in[2],  (const float*)d_in[3],
        (const float*)d_in[4],  (const float*)d_in[5],
        (const float*)d_in[6],
        (const float*)d_in[7],  (const float*)d_in[8],
        (const float*)d_in[9],  (const float*)d_in[10],
        (const float*)d_in[11], (const float*)d_in[12],
        (const float*)d_in[13], (const float*)d_in[14],
        (const float*)d_in[15], (const float*)d_in[16],
        (const float*)d_in[17], (const float*)d_in[18],
        (const float*)d_in[19], (const float*)d_in[20],
        (const float*)d_in[21], (const float*)d_in[22],
        (const float*)d_in[23], (const float*)d_in[24],
        (const float*)d_in[25], (const float*)d_in[26],
        (const float*)d_in[27], (const float*)d_in[28],
        (const float*)d_in[29], (const float*)d_in[30],
        ws);
    recovery_net_kernel<<<NBLOCKS, NTHR, 0, stream>>>(
        (const float*)d_in[0], (const int*)d_in[1], ws, (float2*)d_out);
}

// Round 12
// 81.641 us; speedup vs baseline: 2.1628x; 2.1628x over previous
//
#include <hip/hip_runtime.h>

typedef _Float16 f16x8 __attribute__((ext_vector_type(8)));
typedef __fp16 fp16x2 __attribute__((ext_vector_type(2)));
typedef float f32x4 __attribute__((ext_vector_type(4)));

#define NTHR 256
constexpr float EPS = 1e-5f;
constexpr int NBLOCKS = 4096;   // 4096 x 256 rows

// ---- ws byte offsets ----
#define TAB_B   0       // f16 [29][8]  embedding-MLP table
#define W1_B    1024    // f16 [48][64]  fc1 (bn1+cbn folded, bias at k=36)
#define W2_B    7168    // f16 [32][64]  fc2 (bn2 folded, bias at k=36)
#define W3_B    11264   // f16 [16][32]  fc3 (bn3 folded, bias at k=18)
#define W4_B    12736   // f32 [16]  fc4 delta row (w 0..8, bias at 9)

__device__ __forceinline__ ushort f16bits(float x) {
    union { _Float16 h; ushort u; } c; c.h = (_Float16)x; return c.u;
}
__device__ __forceinline__ uint pk2(float a, float b) {
    union { fp16x2 h; uint u; } c; c.h = __builtin_amdgcn_cvt_pkrtz(a, b); return c.u;
}
__device__ __forceinline__ uint pkrelu(float a, float b) {
    return pk2(fmaxf(a, 0.f), fmaxf(b, 0.f));
}
__device__ __forceinline__ f16x8 mk8(uint a, uint b, uint c, uint d) {
    union { uint u[4]; f16x8 v; } f;
    f.u[0] = a; f.u[1] = b; f.u[2] = c; f.u[3] = d;
    return f.v;
}
__device__ __forceinline__ f16x8 ldw_frag(const ushort* wp, int m, int stride, int kb, int g) {
    const ushort* p = wp + m * stride + kb + 4 * g;
    uint2 lo = *(const uint2*)p;
    uint2 hi = *(const uint2*)(p + 16);
    return mk8(lo.x, lo.y, hi.x, hi.y);
}

__global__ __launch_bounds__(NTHR) void prep_kernel(
    const float* __restrict__ embt, const float* __restrict__ w1,
    const float* __restrict__ b1,   const float* __restrict__ w2,
    const float* __restrict__ b2,
    const float* __restrict__ cbn_g, const float* __restrict__ cbn_b,
    const float* __restrict__ cbn_m, const float* __restrict__ cbn_v,
    const float* __restrict__ f1w, const float* __restrict__ f1b,
    const float* __restrict__ f2w, const float* __restrict__ f2b,
    const float* __restrict__ f3w, const float* __restrict__ f3b,
    const float* __restrict__ f4w, const float* __restrict__ f4b,
    const float* __restrict__ bn1g, const float* __restrict__ bn1b,
    const float* __restrict__ bn1m, const float* __restrict__ bn1v,
    const float* __restrict__ bn2g, const float* __restrict__ bn2b,
    const float* __restrict__ bn2m, const float* __restrict__ bn2v,
    const float* __restrict__ bn3g, const float* __restrict__ bn3b,
    const float* __restrict__ bn3m, const float* __restrict__ bn3v,
    char* __restrict__ ws)
{
    const int t = threadIdx.x;
    ushort* tab = (ushort*)(ws + TAB_B);
    ushort* w1o = (ushort*)(ws + W1_B);
    ushort* w2o = (ushort*)(ws + W2_B);
    ushort* w3o = (ushort*)(ws + W3_B);
    float* w4o = (float*)(ws + W4_B);

    for (int i = t; i < 232; i += NTHR) {
        int j = i / 8, c = i % 8;
        float xe = 0.f;
        if (c < 5) {
            xe = b2[j];
            for (int e = 0; e < 6; e++) {
                float a = b1[j * 6 + e];
                for (int d = 0; d < 6; d++)
                    a += embt[(j * 5 + c) * 6 + d] * w1[j * 36 + d * 6 + e];
                xe += fmaxf(a, 0.f) * w2[j * 6 + e];
            }
        }
        tab[i] = f16bits(xe);
    }
    for (int i = t; i < 3072; i += NTHR) {
        int n = i / 64, k = i % 64;
        float v = 0.f;
        if (n < 36) {
            float s1 = bn1g[n] * rsqrtf(bn1v[n] + EPS);
            if (k < 36) {
                v = f1w[n * 36 + k] * s1;
                if (k < 7) v *= cbn_g[k] * rsqrtf(cbn_v[k] + EPS);
            } else if (k == 36) {
                v = f1b[n] * s1 + bn1b[n] - bn1m[n] * s1;
                for (int kk = 0; kk < 7; kk++) {
                    float cs = cbn_g[kk] * rsqrtf(cbn_v[kk] + EPS);
                    float ct = cbn_b[kk] - cbn_m[kk] * cs;
                    v += f1w[n * 36 + kk] * s1 * ct;
                }
            }
        } else if (n == 36 && k == 36) {
            v = 1.f;
        }
        w1o[i] = f16bits(v);
    }
    for (int i = t; i < 2048; i += NTHR) {
        int n = i / 64, k = i % 64;
        float v = 0.f;
        if (n < 18) {
            float s = bn2g[n] * rsqrtf(bn2v[n] + EPS);
            if (k < 36) v = f2w[n * 36 + k] * s;
            else if (k == 36) v = f2b[n] * s + bn2b[n] - bn2m[n] * s;
        } else if (n == 18 && k == 36) {
            v = 1.f;
        }
        w2o[i] = f16bits(v);
    }
    for (int i = t; i < 512; i += NTHR) {
        int n = i / 32, k = i % 32;
        float v = 0.f;
        if (n < 9) {
            float s = bn3g[n] * rsqrtf(bn3v[n] + EPS);
            if (k < 18) v = f3w[n * 18 + k] * s;
            else if (k == 18) v = f3b[n] * s + bn3b[n] - bn3m[n] * s;
        } else if (n == 9 && k == 18) {
            v = 1.f;
        }
        w3o[i] = f16bits(v);
    }
    if (t < 16) w4o[t] = (t < 9) ? (f4w[9 + t] - f4w[t]) : (t == 9 ? (f4b[1] - f4b[0]) : 0.f);
}

#define XSTRIDE 72

__global__ __launch_bounds__(NTHR, 4) void recovery_net_kernel(
    const float* __restrict__ xcon, const int* __restrict__ xcat,
    const char* __restrict__ ws, float2* __restrict__ out)
{
    // All LDS is wave-private strips — no block barrier anywhere.
    __shared__ __align__(16) char s_x[256 * XSTRIDE];   // 18432 B
    __shared__ uint s_catp[1856];                       // 7424 B packed bytes
    __shared__ ushort s_tab[4][232];                    // per-wave table replica

    const int t = threadIdx.x;
    const int lane = t & 63, w = t >> 6;
    const int l15 = lane & 15, gq = lane >> 4;
    const int rb = w * 64;

    // ---- issue own-row xcon loads first (deep latency, off critical path) ----
    const float* xrow = xcon + ((size_t)blockIdx.x * 256 + t) * 7;
    float v0 = xrow[0], v1 = xrow[1], v2 = xrow[2], v3 = xrow[3];
    float v4 = xrow[4], v5 = xrow[5], v6 = xrow[6];

    // ---- per-wave tab replica (232 f16 = 116 dwords) ----
    for (int idx = lane; idx < 116; idx += 64)
        ((uint*)s_tab[w])[idx] = ((const uint*)(ws + TAB_B))[idx];

    // ---- per-wave xcat staging: coalesced int4 -> packed bytes in own strip ----
    {
        const int4* src = (const int4*)(xcat + ((size_t)blockIdx.x * 256 + rb) * 29);
        for (int idx = lane; idx < 464; idx += 64) {
            int4 v = src[idx];
            s_catp[w * 464 + idx] =
                (uint)(v.x & 0xff) | ((uint)(v.y & 0xff) << 8) |
                ((uint)(v.z & 0xff) << 16) | ((uint)(v.w & 0xff) << 24);
        }
    }
    asm volatile("s_waitcnt lgkmcnt(0)" ::: "memory");

    // ---- X-fill: build own row (f16) and write to own strip ----
    {
        const unsigned char* myc = (const unsigned char*)s_catp + w * 1856 + lane * 29;
        const ushort* tb = s_tab[w];
        ushort th[29];
#pragma unroll
        for (int j = 0; j < 29; j++) th[j] = tb[j * 8 + (int)myc[j]];
        uint wd[18];
        wd[0] = pk2(v0, v1);
        wd[1] = pk2(v2, v3);
        wd[2] = pk2(v4, v5);
        wd[3] = (uint)f16bits(v6) | ((uint)th[0] << 16);
#pragma unroll
        for (int k = 0; k < 14; k++)
            wd[4 + k] = (uint)th[1 + 2 * k] | ((uint)th[2 + 2 * k] << 16);
        char* xb = s_x + t * XSTRIDE;
#pragma unroll
        for (int j = 0; j < 9; j++)
            *(uint2*)(xb + 8 * j) = make_uint2(wd[2 * j], wd[2 * j + 1]);
    }
    asm volatile("s_waitcnt lgkmcnt(0)" ::: "memory");

    // ---- weights resident in registers ----
    const ushort* w1p = (const ushort*)(ws + W1_B);
    const ushort* w2p = (const ushort*)(ws + W2_B);
    const ushort* w3p = (const ushort*)(ws + W3_B);
    f16x8 a1[3][2], a2[2][2], a3;
#pragma unroll
    for (int mt = 0; mt < 3; mt++) {
        a1[mt][0] = ldw_frag(w1p, mt * 16 + l15, 64, 0, gq);
        a1[mt][1] = ldw_frag(w1p, mt * 16 + l15, 64, 32, gq);
    }
#pragma unroll
    for (int mt = 0; mt < 2; mt++) {
        a2[mt][0] = ldw_frag(w2p, mt * 16 + l15, 64, 0, gq);
        a2[mt][1] = ldw_frag(w2p, mt * 16 + l15, 64, 32, gq);
    }
    a3 = ldw_frag(w3p, l15, 32, 0, gq);
    const float4 w4v = *(const float4*)((const float*)(ws + W4_B) + 4 * gq);

    // ---- 4 batch tiles of 16 rows; whole chain in registers ----
#pragma unroll
    for (int bt = 0; bt < 4; bt++) {
        const char* xr = s_x + (rb + 16 * bt + l15) * XSTRIDE;
        uint2 q0 = *(const uint2*)(xr + 8 * gq);
        uint2 q1 = *(const uint2*)(xr + 32 + 8 * gq);
        uint2 q2 = *(const uint2*)(xr + 64);
        f16x8 xb0 = mk8(q0.x, q0.y, q1.x, q1.y);
        uint cw0 = (gq == 0) ? q2.x : (gq == 1 ? 0x00003C00u : 0u);
        uint cw1 = (gq == 0) ? q2.y : 0u;
        f16x8 xb1 = mk8(cw0, cw1, 0u, 0u);

        f32x4 c10 = {0.f, 0.f, 0.f, 0.f};
        f32x4 c11 = {0.f, 0.f, 0.f, 0.f};
        f32x4 c12 = {0.f, 0.f, 0.f, 0.f};
        c10 = __builtin_amdgcn_mfma_f32_16x16x32_f16(a1[0][0], xb0, c10, 0, 0, 0);
        c11 = __builtin_amdgcn_mfma_f32_16x16x32_f16(a1[1][0], xb0, c11, 0, 0, 0);
        c12 = __builtin_amdgcn_mfma_f32_16x16x32_f16(a1[2][0], xb0, c12, 0, 0, 0);
        c10 = __builtin_amdgcn_mfma_f32_16x16x32_f16(a1[0][1], xb1, c10, 0, 0, 0);
        c11 = __builtin_amdgcn_mfma_f32_16x16x32_f16(a1[1][1], xb1, c11, 0, 0, 0);
        c12 = __builtin_amdgcn_mfma_f32_16x16x32_f16(a1[2][1], xb1, c12, 0, 0, 0);

        f16x8 h0 = mk8(pkrelu(c10.x, c10.y), pkrelu(c10.z, c10.w),
                       pkrelu(c11.x, c11.y), pkrelu(c11.z, c11.w));
        f16x8 h1 = mk8(pkrelu(c12.x, c12.y), pkrelu(c12.z, c12.w), 0u, 0u);

        f32x4 c20 = {0.f, 0.f, 0.f, 0.f};
        f32x4 c21 = {0.f, 0.f, 0.f, 0.f};
        c20 = __builtin_amdgcn_mfma_f32_16x16x32_f16(a2[0][0], h0, c20, 0, 0, 0);
        c21 = __builtin_amdgcn_mfma_f32_16x16x32_f16(a2[1][0], h0, c21, 0, 0, 0);
        c20 = __builtin_amdgcn_mfma_f32_16x16x32_f16(a2[0][1], h1, c20, 0, 0, 0);
        c21 = __builtin_amdgcn_mfma_f32_16x16x32_f16(a2[1][1], h1, c21, 0, 0, 0);

        f16x8 h2 = mk8(pkrelu(c20.x, c20.y), pkrelu(c20.z, c20.w),
                       pkrelu(c21.x, c21.y), pkrelu(c21.z, c21.w));
        f32x4 c3 = {0.f, 0.f, 0.f, 0.f};
        c3 = __builtin_amdgcn_mfma_f32_16x16x32_f16(a3, h2, c3, 0, 0, 0);

        float part = fmaxf(c3.x, 0.f) * w4v.x + fmaxf(c3.y, 0.f) * w4v.y +
                     fmaxf(c3.z, 0.f) * w4v.z + fmaxf(c3.w, 0.f) * w4v.w;
        part += __shfl_xor(part, 16);
        part += __shfl_xor(part, 32);
        float p1v = 1.f / (1.f + __expf(-part));
        if (gq == 0)
            out[(size_t)blockIdx.x * 256 + rb + 16 * bt + l15] = make_float2(1.f - p1v, p1v);
    }
}

extern "C" void kernel_launch(void* const* d_in, const int* in_sizes, int n_in,
                              void* d_out, int out_size, void* d_ws, size_t ws_size,
                              hipStream_t stream) {
    (void)in_sizes; (void)n_in; (void)ws_size; (void)out_size;
    char* ws = (char*)d_ws;
    prep_kernel<<<1, NTHR, 0, stream>>>(
        (const float*)d_in[2],  (const float*)d_in[3],
        (const float*)d_in[4],  (const float*)d_in[5],
        (const float*)d_in[6],
        (const float*)d_in[7],  (const float*)d_in[8],
        (const float*)d_in[9],  (const float*)d_in[10],
        (const float*)d_in[11], (const float*)d_in[12],
        (const float*)d_in[13], (const float*)d_in[14],
        (const float*)d_in[15], (const float*)d_in[16],
        (const float*)d_in[17], (const float*)d_in[18],
        (const float*)d_in[19], (const float*)d_in[20],
        (const float*)d_in[21], (const float*)d_in[22],
        (const float*)d_in[23], (const float*)d_in[24],
        (const float*)d_in[25], (const float*)d_in[26],
        (const float*)d_in[27], (const float*)d_in[28],
        (const float*)d_in[29], (const float*)d_in[30],
        ws);
    recovery_net_kernel<<<NBLOCKS, NTHR, 0, stream>>>(
        (const float*)d_in[0], (const int*)d_in[1], ws, (float2*)d_out);
}